// Round 15
// baseline (290.799 us; speedup 1.0000x reference)
//
#include <hip/hip_runtime.h>
#include <stdint.h>

// B=8, S=2048, D=512, H=512 self-attention. ws = 256MiB.
// r14: gemm256 sync changed to counted-vmcnt (T4): stage(kt+1) stays in
// flight across the MFMA phase; barriers never drain vmcnt to 0 mid-loop.

typedef __attribute__((ext_vector_type(4))) float f32x4;
typedef __attribute__((ext_vector_type(8))) short short8;
typedef __attribute__((ext_vector_type(4))) unsigned short ushort4v;
typedef __attribute__((ext_vector_type(8))) unsigned short ushort8v;
typedef unsigned short bf16_t;

#define AS1 __attribute__((address_space(1)))
#define AS3 __attribute__((address_space(3)))

static __device__ __forceinline__ unsigned short f2bf(float f) {
  unsigned int u = __float_as_uint(f);
  u += 0x7fffu + ((u >> 16) & 1u);   // round-to-nearest-even
  return (unsigned short)(u >> 16);
}
static __device__ __forceinline__ float bf2f(unsigned short h) {
  return __uint_as_float(((unsigned int)h) << 16);
}

static __device__ __forceinline__ void bar() {
  asm volatile("" ::: "memory");
  __builtin_amdgcn_s_barrier();
  asm volatile("" ::: "memory");
}
template <int N>
static __device__ __forceinline__ void wait_vm() {
  if constexpr (N == 8)      asm volatile("s_waitcnt vmcnt(8)" ::: "memory");
  else if constexpr (N == 6) asm volatile("s_waitcnt vmcnt(6)" ::: "memory");
  else                       asm volatile("s_waitcnt vmcnt(0)" ::: "memory");
}

__global__ __launch_bounds__(256) void ws_sentinel(float* out) {
  out[threadIdx.x] = 1e30f;
}

// ---------------- cast float -> bf16 (vector x4) ----------------
__global__ __launch_bounds__(256) void cast_f32_bf16(
    const float* __restrict__ in, bf16_t* __restrict__ out, int n4) {
  int i = blockIdx.x * 256 + threadIdx.x;
  if (i >= n4) return;
  float4 v = ((const float4*)in)[i];
  ushort4v o = { f2bf(v.x), f2bf(v.y), f2bf(v.z), f2bf(v.w) };
  ((ushort4v*)out)[i] = o;
}

// ------- batched cast+transpose of the four 512x512 weights (z=0..3) -------
__global__ __launch_bounds__(256) void cast_transpose_w(
    const float* __restrict__ Wq, const float* __restrict__ Wk,
    const float* __restrict__ Wv, const float* __restrict__ Wo,
    bf16_t* __restrict__ WqkvT, bf16_t* __restrict__ WoT) {
  __shared__ float tile[32][33];
  int z = blockIdx.z;
  const float* in = (z == 0) ? Wq : (z == 1) ? Wk : (z == 2) ? Wv : Wo;
  bf16_t* out = (z < 3) ? WqkvT + z * 512 * 512 : WoT;
  int bx = blockIdx.x * 32;
  int by = blockIdx.y * 32;
  int tx = threadIdx.x & 31;
  int ty = threadIdx.x >> 5;  // 0..7
#pragma unroll
  for (int k = 0; k < 4; ++k)
    tile[ty + k * 8][tx] = in[(by + ty + k * 8) * 512 + bx + tx];
  __syncthreads();
#pragma unroll
  for (int k = 0; k < 4; ++k)
    out[(bx + ty + k * 8) * 512 + by + tx] = f2bf(tile[tx][ty + k * 8]);
}

// ---------------- concat 3 biases [512] -> [1536] ----------------
__global__ __launch_bounds__(256) void concat_bias(
    const float* __restrict__ b0, const float* __restrict__ b1,
    const float* __restrict__ b2, float* __restrict__ out) {
  int i = blockIdx.x * 256 + threadIdx.x;  // 0..1535
  const float* src = (i < 512) ? b0 : (i < 1024) ? b1 : b2;
  out[i] = src[i & 511];
}

// ---------------- gemm_bt: 128x128 tile, 4 waves (validated r8 core) -------
template <typename OT>
__global__ __launch_bounds__(256, 2) void gemm_bt(
    const bf16_t* __restrict__ A, int lda, long sA,
    const bf16_t* __restrict__ BT, int ldb, long sB,
    const float* __restrict__ bias, const float* __restrict__ resid,
    bf16_t* __restrict__ vt_out,
    OT* __restrict__ Cout, int ldc, long sC, int M, int N, int K, float scale) {
  __shared__ __align__(16) bf16_t As[128 * 64];
  __shared__ __align__(16) bf16_t Bs[128 * 64];
  const int z = blockIdx.z;
  const bf16_t* Ab = A + (long)z * sA;
  const bf16_t* Bb = BT + (long)z * sB;
  const int tile_m = blockIdx.x * 128;
  const int tile_n = blockIdx.y * 128;
  const int t = threadIdx.x;
  const int lane = t & 63;
  const int wave = t >> 6;
  const int wm = (wave >> 1) * 64;
  const int wn = (wave & 1) * 64;

  f32x4 acc[4][4];
#pragma unroll
  for (int i = 0; i < 4; ++i)
#pragma unroll
    for (int j = 0; j < 4; ++j) acc[i][j] = f32x4{0.f, 0.f, 0.f, 0.f};

  const bf16_t* gA[4];
  const bf16_t* gB[4];
  int ldsoff[4];
#pragma unroll
  for (int i = 0; i < 4; ++i) {
    int o16 = i * 256 + t;
    int row = o16 >> 3;
    int slot = (o16 & 7) ^ (row & 7);
    gA[i] = Ab + (long)(tile_m + row) * lda + slot * 8;
    gB[i] = Bb + (long)(tile_n + row) * ldb + slot * 8;
    ldsoff[i] = o16 * 8;
  }

  const int nk = K >> 6;
  for (int kt = 0; kt < nk; ++kt) {
#pragma unroll
    for (int i = 0; i < 4; ++i) {
      __builtin_amdgcn_global_load_lds((const AS1 unsigned int*)(gA[i]),
                                       (AS3 unsigned int*)(&As[ldsoff[i]]),
                                       16, 0, 0);
      __builtin_amdgcn_global_load_lds((const AS1 unsigned int*)(gB[i]),
                                       (AS3 unsigned int*)(&Bs[ldsoff[i]]),
                                       16, 0, 0);
      gA[i] += 64;
      gB[i] += 64;
    }
    __syncthreads();
#pragma unroll
    for (int ks = 0; ks < 2; ++ks) {
      short8 af[4], bfr[4];
#pragma unroll
      for (int i = 0; i < 4; ++i) {
        int ra = wm + i * 16 + (lane & 15);
        int oa = ra * 128 + ((ks * 64 + (lane >> 4) * 16) ^ ((ra & 7) << 4));
        af[i] = *(const short8*)((const char*)As + oa);
        int rb = wn + i * 16 + (lane & 15);
        int ob = rb * 128 + ((ks * 64 + (lane >> 4) * 16) ^ ((rb & 7) << 4));
        bfr[i] = *(const short8*)((const char*)Bs + ob);
      }
#pragma unroll
      for (int i = 0; i < 4; ++i)
#pragma unroll
        for (int j = 0; j < 4; ++j)
          acc[i][j] = __builtin_amdgcn_mfma_f32_16x16x32_bf16(
              af[i], bfr[j], acc[i][j], 0, 0, 0);
    }
    __syncthreads();
  }

  OT* Cz = Cout + (long)z * sC;
#pragma unroll
  for (int i = 0; i < 4; ++i) {
    int crow0 = tile_m + wm + i * 16 + ((lane >> 4) << 2);
#pragma unroll
    for (int j = 0; j < 4; ++j) {
      int ccol = tile_n + wn + j * 16 + (lane & 15);
      float bv = bias ? bias[ccol] : 0.f;
      if (vt_out && ccol >= 1024) {       // V slice -> transposed store
        int c = ccol - 1024;
#pragma unroll
        for (int r = 0; r < 4; ++r) {
          int rr = crow0 + r;
          float val = acc[i][j][r] * scale + bv;
          vt_out[((long)(rr >> 11) << 20) + ((long)c << 11) + (rr & 2047)] =
              f2bf(val);
        }
      } else {
#pragma unroll
        for (int r = 0; r < 4; ++r) {
          long idx = (long)(crow0 + r) * ldc + ccol;
          float val = acc[i][j][r] * scale + bv;
          if (resid) val += resid[idx];
          if constexpr (sizeof(OT) == 2)
            Cz[idx] = (OT)f2bf(val);
          else
            Cz[idx] = (OT)val;
        }
      }
    }
  }
}

// ------- gemm256<BN>: 256xBN tile, 8 waves (2Mx4N), dbuf + counted vmcnt ---
// Loop: bar1 (prior reads of buf^1 done) -> issue stage(kt+1)->buf^1 ->
// vmcnt(IN_FLIGHT) (stage(kt) landed, kt+1 in flight) -> bar2 (publish) ->
// ds_read buf + MFMA. No vmcnt(0) drain in the main loop (T4, m218).
template <int BN>
__global__ __launch_bounds__(512, 2) void gemm256(
    const bf16_t* __restrict__ A, int lda, long sA,
    const bf16_t* __restrict__ BT, int ldb, long sB,
    bf16_t* __restrict__ Cout, int ldc, long sC, int K, float scale) {
  constexpr int JF = BN / 64;        // N-frags per wave (4 or 2)
  constexpr int BCH = BN * 8 / 512;  // B gload chunks per thread (4 or 2)
  constexpr int INF = 4 + BCH;       // loads issued per iter (8 or 6)
  __shared__ __align__(16) bf16_t As[2][256 * 64];
  __shared__ __align__(16) bf16_t Bs[2][BN * 64];
  const int z = blockIdx.z;
  const bf16_t* Ab = A + (long)z * sA;
  const bf16_t* Bb = BT + (long)z * sB;
  const int tile_m = blockIdx.x * 256;
  const int tile_n = blockIdx.y * BN;
  const int t = threadIdx.x;          // 0..511
  const int lane = t & 63;
  const int wave = t >> 6;            // 0..7
  const int wm = (wave >> 2) * 128;   // 0 or 128
  const int wn = (wave & 3) * (BN / 4);

  f32x4 acc[8][JF];
#pragma unroll
  for (int i = 0; i < 8; ++i)
#pragma unroll
    for (int j = 0; j < JF; ++j) acc[i][j] = f32x4{0.f, 0.f, 0.f, 0.f};

  const bf16_t* gA[4];
  int ldsA[4];
#pragma unroll
  for (int k = 0; k < 4; ++k) {
    int c = k * 512 + t;               // chunk 0..2047
    int row = c >> 3;                  // 0..255
    int slot = (c & 7) ^ (row & 7);    // inverse swizzle on source
    gA[k] = Ab + (long)(tile_m + row) * lda + slot * 8;
    ldsA[k] = c * 8;
  }
  const bf16_t* gB[BCH];
  int ldsB[BCH];
#pragma unroll
  for (int k = 0; k < BCH; ++k) {
    int c = k * 512 + t;
    int row = c >> 3;
    int slot = (c & 7) ^ (row & 7);
    gB[k] = Bb + (long)(tile_n + row) * ldb + slot * 8;
    ldsB[k] = c * 8;
  }

  const int nk = K >> 6;
  int buf = 0;
  // prologue: stage K-tile 0 into buf 0 (INF loads in flight)
#pragma unroll
  for (int k = 0; k < 4; ++k)
    __builtin_amdgcn_global_load_lds((const AS1 unsigned int*)(gA[k]),
                                     (AS3 unsigned int*)(&As[0][ldsA[k]]),
                                     16, 0, 0);
#pragma unroll
  for (int k = 0; k < BCH; ++k)
    __builtin_amdgcn_global_load_lds((const AS1 unsigned int*)(gB[k]),
                                     (AS3 unsigned int*)(&Bs[0][ldsB[k]]),
                                     16, 0, 0);

  for (int kt = 0; kt < nk; ++kt) {
    bar();  // all prior-iter ds_reads of buf^1 complete -> safe to overwrite
    if (kt + 1 < nk) {
      long koff = (long)(kt + 1) * 64;
#pragma unroll
      for (int k = 0; k < 4; ++k)
        __builtin_amdgcn_global_load_lds(
            (const AS1 unsigned int*)(gA[k] + koff),
            (AS3 unsigned int*)(&As[buf ^ 1][ldsA[k]]), 16, 0, 0);
#pragma unroll
      for (int k = 0; k < BCH; ++k)
        __builtin_amdgcn_global_load_lds(
            (const AS1 unsigned int*)(gB[k] + koff),
            (AS3 unsigned int*)(&Bs[buf ^ 1][ldsB[k]]), 16, 0, 0);
      wait_vm<INF>();  // stage(kt) landed; stage(kt+1) stays in flight
    } else {
      wait_vm<0>();    // epilogue drain
    }
    bar();  // publish stage(kt) to all waves
    const char* Ap = (const char*)As[buf];
    const char* Bp = (const char*)Bs[buf];
#pragma unroll
    for (int ks = 0; ks < 2; ++ks) {
      short8 af[8], bfr[JF];
#pragma unroll
      for (int i = 0; i < 8; ++i) {
        int ra = wm + i * 16 + (lane & 15);
        int oa = ra * 128 + ((ks * 64 + (lane >> 4) * 16) ^ ((ra & 7) << 4));
        af[i] = *(const short8*)(Ap + oa);
      }
#pragma unroll
      for (int j = 0; j < JF; ++j) {
        int rb = wn + j * 16 + (lane & 15);
        int ob = rb * 128 + ((ks * 64 + (lane >> 4) * 16) ^ ((rb & 7) << 4));
        bfr[j] = *(const short8*)(Bp + ob);
      }
#pragma unroll
      for (int i = 0; i < 8; ++i)
#pragma unroll
        for (int j = 0; j < JF; ++j)
          acc[i][j] = __builtin_amdgcn_mfma_f32_16x16x32_bf16(
              af[i], bfr[j], acc[i][j], 0, 0, 0);
    }
    buf ^= 1;
  }

  // epilogue: C/D layout col=lane&15, row=(lane>>4)*4+reg  [m89-verified]
  bf16_t* Cz = Cout + (long)z * sC;
#pragma unroll
  for (int i = 0; i < 8; ++i) {
    int crow0 = tile_m + wm + i * 16 + ((lane >> 4) << 2);
#pragma unroll
    for (int j = 0; j < JF; ++j) {
      int ccol = tile_n + wn + j * 16 + (lane & 15);
#pragma unroll
      for (int r = 0; r < 4; ++r)
        Cz[(long)(crow0 + r) * ldc + ccol] = f2bf(acc[i][j][r] * scale);
    }
  }
}

// ------- row softmax IN-PLACE on bf16 scores: row [2048] bf16 -> P bf16 ----
__global__ __launch_bounds__(256, 4) void softmax_rows_bf16(
    bf16_t* __restrict__ S) {
  long row = blockIdx.x;
  bf16_t* srow = S + row * 2048;
  int t = threadIdx.x;
  ushort8v v = *(ushort8v*)(srow + t * 8);
  float e[8];
#pragma unroll
  for (int k = 0; k < 8; ++k) e[k] = bf2f(v[k]);
  float m = e[0];
#pragma unroll
  for (int k = 1; k < 8; ++k) m = fmaxf(m, e[k]);
#pragma unroll
  for (int off = 32; off; off >>= 1) m = fmaxf(m, __shfl_xor(m, off, 64));
  __shared__ float red[8];
  if ((t & 63) == 0) red[t >> 6] = m;
  __syncthreads();
  m = fmaxf(fmaxf(red[0], red[1]), fmaxf(red[2], red[3]));
  float s = 0.f;
#pragma unroll
  for (int k = 0; k < 8; ++k) {
    e[k] = __expf(e[k] - m);
    s += e[k];
  }
#pragma unroll
  for (int off = 32; off; off >>= 1) s += __shfl_xor(s, off, 64);
  if ((t & 63) == 0) red[4 + (t >> 6)] = s;
  __syncthreads();
  s = (red[4] + red[5]) + (red[6] + red[7]);
  float inv = 1.0f / s;
  ushort8v o;
#pragma unroll
  for (int k = 0; k < 8; ++k) o[k] = f2bf(e[k] * inv);
  *(ushort8v*)(srow + t * 8) = o;   // exact same 16B this thread read
}

extern "C" void kernel_launch(void* const* d_in, const int* in_sizes, int n_in,
                              void* d_out, int out_size, void* d_ws,
                              size_t ws_size, hipStream_t stream) {
  const float* x  = (const float*)d_in[0];
  const float* Wq = (const float*)d_in[1];
  const float* bq = (const float*)d_in[2];
  const float* Wk = (const float*)d_in[3];
  const float* bk = (const float*)d_in[4];
  const float* Wv = (const float*)d_in[5];
  const float* bv = (const float*)d_in[6];
  const float* Wo = (const float*)d_in[7];
  const float* bo = (const float*)d_in[8];
  float* out = (float*)d_out;

  const int S = 2048, D = 512;
  const long MS = 16384;               // B*S
  const long MB = 1024 * 1024;

  // Workspace layout (unchanged from r8):
  //  [0,16M):    xb bf16 [16384][512]   -> reused as ctx after QKV GEMM
  //  [16,64M):   QKV bf16 [16384][1536] (V slice unwritten; V goes to VT)
  //  [64,80M):   VT bf16 [8][512][2048]
  //  [80,144M):  Sc bf16 [8][2048][2048] (softmax in-place -> P)
  //  [144,147M): WqkvT bf16 [1536][512], WoT bf16 [512][512], bqkv f32[1536]
  const size_t need = 147 * MB;
  if (ws_size < need) {
    ws_sentinel<<<1, 256, 0, stream>>>(out);
    return;
  }
  char* w = (char*)d_ws;
  bf16_t* xb    = (bf16_t*)(w);
  bf16_t* ctx   = (bf16_t*)(w);             // overlays xb (dead after QKV)
  bf16_t* QKV   = (bf16_t*)(w + 16 * MB);
  bf16_t* VT    = (bf16_t*)(w + 64 * MB);
  bf16_t* Sc    = (bf16_t*)(w + 80 * MB);
  bf16_t* WqkvT = (bf16_t*)(w + 144 * MB);  // [1536][512]
  bf16_t* WoT   = WqkvT + 1536 * 512;
  float*  bqkv  = (float*)(WoT + 512 * 512);

  // 1. casts + weight transposes + bias concat
  cast_f32_bf16<<<dim3(8192), 256, 0, stream>>>(x, xb, (int)(MS * D / 4));
  cast_transpose_w<<<dim3(16, 16, 4), 256, 0, stream>>>(Wq, Wk, Wv, Wo,
                                                        WqkvT, WoT);
  concat_bias<<<dim3(6), 256, 0, stream>>>(bq, bk, bv, bqkv);

  // 2. fused QKV projection; V columns written transposed into VT
  gemm_bt<bf16_t><<<dim3(128, 12), 256, 0, stream>>>(
      xb, 512, 0, WqkvT, 512, 0, bqkv, nullptr, VT,
      QKV, 1536, 0, 16384, 1536, 512, 1.0f);

  // 3. scores = Q x K^T / sqrt(H): 256² counted-vmcnt kernel, bf16 out
  const float rsq = 0.04419417382415922f;  // 1/sqrt(512)
  gemm256<256><<<dim3(8, 8, 8), 512, 0, stream>>>(
      QKV, 1536, (long)S * 1536, QKV + 512, 1536, (long)S * 1536,
      Sc, 2048, (long)S * S, 512, rsq);

  // 4. softmax rows in-place (bf16 -> bf16)
  softmax_rows_bf16<<<dim3(16384), 256, 0, stream>>>(Sc);

  // 5. ctx = P x VT^T: 256x128 counted-vmcnt kernel
  gemm256<128><<<dim3(8, 4, 8), 512, 0, stream>>>(
      Sc, 2048, (long)S * 2048, VT, 2048, (long)512 * S,
      ctx, 512, (long)S * 512, 2048, 1.0f);

  // 6. out = ctx x Wo^T + bo + x  (fp32)
  gemm_bt<float><<<dim3(128, 4), 256, 0, stream>>>(
      ctx, 512, 0, WoT, 512, 0, bo, x, nullptr, out, 512, 0,
      16384, 512, 512, 1.0f);
}